// Round 1
// baseline (651.488 us; speedup 1.0000x reference)
//
#include <hip/hip_runtime.h>
#include <hip/hip_bf16.h>
#include <stdint.h>

typedef unsigned short u16;
typedef u16 u16x4 __attribute__((ext_vector_type(4)));
typedef __bf16 bf16x8 __attribute__((ext_vector_type(8)));
typedef float f32x4 __attribute__((ext_vector_type(4)));

#define DEVI __device__ __forceinline__

DEVI u16 f2b(float f) {
  __hip_bfloat16 h = __float2bfloat16(f);
  return __builtin_bit_cast(u16, h);
}

DEVI f32x4 mfma16(bf16x8 a, bf16x8 b, f32x4 c) {
  return __builtin_amdgcn_mfma_f32_16x16x32_bf16(a, b, c, 0, 0, 0);
}

DEVI void gld_lds16(const u16* g, u16* l) {
  __builtin_amdgcn_global_load_lds(
      (const __attribute__((address_space(1))) unsigned int*)g,
      (__attribute__((address_space(3))) unsigned int*)l, 16, 0, 0);
}

// ---------------- convert f32 -> bf16 for x, Wq, Wk, Wv, Wo ----------------
__global__ void cvt_all(const float4* __restrict__ x, const float4* __restrict__ wq,
                        const float4* __restrict__ wk, const float4* __restrict__ wv,
                        const float4* __restrict__ wo,
                        u16x4* __restrict__ xb, u16x4* __restrict__ wqb,
                        u16x4* __restrict__ wkb, u16x4* __restrict__ wvb,
                        u16x4* __restrict__ wob) {
  long i = (long)blockIdx.x * 256 + threadIdx.x;  // 4718592 quads total
  const float4* src; u16x4* dst; long o;
  if (i < 2097152)      { src = x;  dst = xb;  o = i; }
  else if (i < 3145728) { src = wq; dst = wqb; o = i - 2097152; }
  else if (i < 3407872) { src = wk; dst = wkb; o = i - 3145728; }
  else if (i < 3670016) { src = wv; dst = wvb; o = i - 3407872; }
  else                  { src = wo; dst = wob; o = i - 3670016; }
  float4 v = src[o];
  u16x4 r = { f2b(v.x), f2b(v.y), f2b(v.z), f2b(v.w) };
  dst[o] = r;
}

// ---------------- rope cos/sin table [S=2048][D/2=1024] ----------------
__global__ void rope_table(float* __restrict__ cosT, float* __restrict__ sinT) {
  int i = blockIdx.x * 256 + threadIdx.x;  // 2097152
  int s = i >> 10, p = i & 1023;
  // freq = 10000^(-p/1024) = exp2(-p * log2(10000)/1024)
  float freq = exp2f((float)p * -0.012976281620653759f);
  float ang = (float)s * freq;
  float sv, cv;
  sincosf(ang, &sv, &cv);
  cosT[i] = cv;
  sinT[i] = sv;
}

// ---------------- GEMM: C[M,N] = A[M,K] * Bw[N,K]^T (bf16 in, f32 acc) -----
// 128x128 tile, BK=32, 256 threads = 4 waves (2x2), 64x64 per wave.
// EPI 0: f32 row-major store to Cout. EPI 1: V-transpose store bf16 to
//        Vt[b][kvh][hd][s]  (N=512 path).
template <int EPI>
__global__ __launch_bounds__(256)
void gemm_bt(const u16* __restrict__ A, const u16* __restrict__ Bw,
             void* __restrict__ Cout, int M, int N, int K) {
  __shared__ __align__(16) u16 lds[2][2][4096];  // [buf][A/B][128*32]
  const int tid = threadIdx.x;
  const int lane = tid & 63;
  const int w = tid >> 6;
  const int wr = w >> 1, wc = w & 1;
  const int m0 = blockIdx.y << 7, n0 = blockIdx.x << 7;

  const int srow = tid >> 2;
  const int schunk = (tid & 3) << 3;
  const u16* ga0 = A + (size_t)(m0 + srow) * K + schunk;
  const u16* gb0 = Bw + (size_t)(n0 + srow) * K + schunk;
  const size_t rstep = (size_t)64 * K;

  f32x4 acc[4][4] = {};
  const int nk = K >> 5;
  int cur = 0;

  {
    u16* la = &lds[0][0][tid << 3];
    u16* lb = &lds[0][1][tid << 3];
    gld_lds16(ga0, la);
    gld_lds16(ga0 + rstep, la + 2048);
    gld_lds16(gb0, lb);
    gld_lds16(gb0 + rstep, lb + 2048);
  }
  __syncthreads();

  const int l15 = lane & 15;
  const int kcol = (lane >> 4) << 3;
  const int arow = ((wr << 6) + l15) << 5;  // elem offset: row*32
  const int brow = ((wc << 6) + l15) << 5;

  for (int kt = 0; kt < nk; ++kt) {
    if (kt + 1 < nk) {
      const u16* ga = ga0 + ((size_t)(kt + 1) << 5);
      const u16* gb = gb0 + ((size_t)(kt + 1) << 5);
      u16* la = &lds[cur ^ 1][0][tid << 3];
      u16* lb = &lds[cur ^ 1][1][tid << 3];
      gld_lds16(ga, la);
      gld_lds16(ga + rstep, la + 2048);
      gld_lds16(gb, lb);
      gld_lds16(gb + rstep, lb + 2048);
    }
    const u16* la = &lds[cur][0][0];
    const u16* lb = &lds[cur][1][0];
    bf16x8 af[4], bfr[4];
#pragma unroll
    for (int mi = 0; mi < 4; ++mi)
      af[mi] = *(const bf16x8*)&la[arow + (mi << 9) + kcol];
#pragma unroll
    for (int ni = 0; ni < 4; ++ni)
      bfr[ni] = *(const bf16x8*)&lb[brow + (ni << 9) + kcol];
#pragma unroll
    for (int mi = 0; mi < 4; ++mi)
#pragma unroll
      for (int ni = 0; ni < 4; ++ni)
        acc[mi][ni] = mfma16(af[mi], bfr[ni], acc[mi][ni]);
    __syncthreads();
    cur ^= 1;
  }

  const int crow = (lane >> 4) << 2;
  const int ccol = lane & 15;
  if (EPI == 0) {
    float* C = (float*)Cout;
#pragma unroll
    for (int mi = 0; mi < 4; ++mi) {
      int row = m0 + (wr << 6) + (mi << 4) + crow;
#pragma unroll
      for (int ni = 0; ni < 4; ++ni) {
        int col = n0 + (wc << 6) + (ni << 4) + ccol;
#pragma unroll
        for (int rr = 0; rr < 4; ++rr)
          C[(size_t)(row + rr) * N + col] = acc[mi][ni][rr];
      }
    }
  } else {
    u16* Vt = (u16*)Cout;
#pragma unroll
    for (int mi = 0; mi < 4; ++mi) {
      int sg = m0 + (wr << 6) + (mi << 4) + crow;  // global row = b*2048+s
      int b = sg >> 11, s = sg & 2047;
#pragma unroll
      for (int ni = 0; ni < 4; ++ni) {
        int n = n0 + (wc << 6) + (ni << 4) + ccol;  // n = kvh*128+hd
        u16x4 pk = { f2b(acc[mi][ni][0]), f2b(acc[mi][ni][1]),
                     f2b(acc[mi][ni][2]), f2b(acc[mi][ni][3]) };
        *(u16x4*)&Vt[((size_t)((b << 2) + (n >> 7)) * 128 + (n & 127)) * 2048 + s] = pk;
      }
    }
  }
}

// ---------------- rope Q: Qtmp f32 [4096][2048] -> Qh bf16 [B][NH][S][HD] --
// fold in 1/sqrt(2048) score scale.
__global__ void rope_q(const float2* __restrict__ Qtmp, const float* __restrict__ cosT,
                       const float* __restrict__ sinT, u16* __restrict__ Qh) {
  int i = blockIdx.x * 256 + threadIdx.x;  // 4194304 pairs
  int pr = i & 1023;
  int row = i >> 10;
  int s = row & 2047, b = row >> 11;
  float2 v = Qtmp[(size_t)row * 1024 + pr];
  float c = cosT[(s << 10) + pr], sn = sinT[(s << 10) + pr];
  const float SC = 0.022097086912079608f;  // 1/sqrt(2048)
  float yr = (v.x * c - v.y * sn) * SC;
  float yi = (v.x * sn + v.y * c) * SC;
  int h = pr >> 6, hp = pr & 63;
  size_t off = ((size_t)(b * 16 + h) * 2048 + s) * 128 + hp * 2;
  unsigned pk = (unsigned)f2b(yr) | ((unsigned)f2b(yi) << 16);
  *(unsigned*)&Qh[off] = pk;
}

// ---------------- rope K: Ktmp f32 [4096][512] -> Kh bf16 [B][NH][S][HD] ---
// head h uses raw kv-head h/4 with full-D frequencies of head h's span.
__global__ void rope_k(const float2* __restrict__ Ktmp, const float* __restrict__ cosT,
                       const float* __restrict__ sinT, u16* __restrict__ Kh) {
  int i = blockIdx.x * 256 + threadIdx.x;  // 4194304
  int hp = i & 63;
  int h = (i >> 6) & 15;
  int row = i >> 10;
  int s = row & 2047, b = row >> 11;
  float2 v = Ktmp[(size_t)row * 256 + ((h >> 2) << 6) + hp];
  int p = (h << 6) + hp;  // global pair index = (h*128+hd)/2
  float c = cosT[(s << 10) + p], sn = sinT[(s << 10) + p];
  float yr = v.x * c - v.y * sn;
  float yi = v.x * sn + v.y * c;
  size_t off = ((size_t)(b * 16 + h) * 2048 + s) * 128 + hp * 2;
  unsigned pk = (unsigned)f2b(yr) | ((unsigned)f2b(yi) << 16);
  *(unsigned*)&Kh[off] = pk;
}

// ---------------- flash attention -----------------------------------------
// grid: B*NH*(S/64) blocks, 256 thr = 4 independent waves, 16 q-rows/wave.
// K-tiles of 32 keys; online softmax; scale already folded into Q.
__global__ __launch_bounds__(256)
void attn_kernel(const u16* __restrict__ Qh, const u16* __restrict__ Kh,
                 const u16* __restrict__ Vt, u16* __restrict__ attnO) {
  __shared__ __align__(16) u16 plds[4][16][40];  // padded: conflict-free b128 reads
  const int tid = threadIdx.x, lane = tid & 63, w = tid >> 6;
  const int bid = blockIdx.x;
  const int qt = bid & 31, h = (bid >> 5) & 15, b = bid >> 9;
  const int qbase = (qt << 6) + (w << 4);

  const u16* Qp = Qh + (size_t)(b * 16 + h) * 2048 * 128;
  const u16* Kp = Kh + (size_t)(b * 16 + h) * 2048 * 128;
  const u16* Vp = Vt + (size_t)((b << 2) + (h >> 2)) * 128 * 2048;

  const int l15 = lane & 15, lg = lane >> 4;
  const int kcol = lg << 3;

  bf16x8 qf[4];
#pragma unroll
  for (int kb = 0; kb < 4; ++kb)
    qf[kb] = *(const bf16x8*)&Qp[(size_t)(qbase + l15) * 128 + (kb << 5) + kcol];

  f32x4 oacc[8] = {};
  float m[4] = {-1e30f, -1e30f, -1e30f, -1e30f};
  float lsum[4] = {0.f, 0.f, 0.f, 0.f};

  const int nkt = (qbase + 47) >> 5;
  for (int kt = 0; kt < nkt; ++kt) {
    f32x4 sc[2] = {};
#pragma unroll
    for (int kb2 = 0; kb2 < 2; ++kb2) {
      const u16* kbase = &Kp[(size_t)((kt << 5) + (kb2 << 4) + l15) * 128 + kcol];
#pragma unroll
      for (int kb = 0; kb < 4; ++kb) {
        bf16x8 kf = *(const bf16x8*)&kbase[kb << 5];
        sc[kb2] = mfma16(qf[kb], kf, sc[kb2]);
      }
    }
    if (kt == nkt - 1) {  // causal boundary tile
#pragma unroll
      for (int kb2 = 0; kb2 < 2; ++kb2) {
        int key = (kt << 5) + (kb2 << 4) + l15;
#pragma unroll
        for (int r = 0; r < 4; ++r) {
          int qr = qbase + (lg << 2) + r;
          if (key > qr) sc[kb2][r] = -1e30f;
        }
      }
    }
    float rmax[4], alpha[4], p0[4], p1[4], rs[4];
#pragma unroll
    for (int r = 0; r < 4; ++r) rmax[r] = fmaxf(sc[0][r], sc[1][r]);
#pragma unroll
    for (int xm = 1; xm <= 8; xm <<= 1)
#pragma unroll
      for (int r = 0; r < 4; ++r)
        rmax[r] = fmaxf(rmax[r], __shfl_xor(rmax[r], xm));
#pragma unroll
    for (int r = 0; r < 4; ++r) {
      float nm = fmaxf(m[r], rmax[r]);
      alpha[r] = __expf(m[r] - nm);
      m[r] = nm;
      p0[r] = __expf(sc[0][r] - nm);
      p1[r] = __expf(sc[1][r] - nm);
      rs[r] = p0[r] + p1[r];
    }
#pragma unroll
    for (int xm = 1; xm <= 8; xm <<= 1)
#pragma unroll
      for (int r = 0; r < 4; ++r)
        rs[r] += __shfl_xor(rs[r], xm);
#pragma unroll
    for (int r = 0; r < 4; ++r) lsum[r] = lsum[r] * alpha[r] + rs[r];
#pragma unroll
    for (int hb = 0; hb < 8; ++hb)
#pragma unroll
      for (int r = 0; r < 4; ++r)
        oacc[hb][r] *= alpha[r];
    // P (acc layout) -> LDS -> A-fragment layout
#pragma unroll
    for (int r = 0; r < 4; ++r) {
      plds[w][(lg << 2) + r][l15] = f2b(p0[r]);
      plds[w][(lg << 2) + r][16 + l15] = f2b(p1[r]);
    }
    bf16x8 pa = *(const bf16x8*)&plds[w][l15][kcol];
    const u16* vbase = &Vp[(size_t)l15 * 2048 + (kt << 5) + kcol];
#pragma unroll
    for (int hb = 0; hb < 8; ++hb) {
      bf16x8 vf = *(const bf16x8*)&vbase[(size_t)(hb << 4) * 2048];
      oacc[hb] = mfma16(pa, vf, oacc[hb]);
    }
  }

  float inv[4];
#pragma unroll
  for (int r = 0; r < 4; ++r) inv[r] = 1.0f / lsum[r];
  u16* op = attnO + (size_t)(b * 2048 + qbase) * 2048 + h * 128;
#pragma unroll
  for (int hb = 0; hb < 8; ++hb)
#pragma unroll
    for (int r = 0; r < 4; ++r)
      op[(size_t)((lg << 2) + r) * 2048 + (hb << 4) + l15] = f2b(oacc[hb][r] * inv[r]);
}

// ---------------------------------------------------------------------------
extern "C" void kernel_launch(void* const* d_in, const int* in_sizes, int n_in,
                              void* d_out, int out_size, void* d_ws, size_t ws_size,
                              hipStream_t stream) {
  const float* x  = (const float*)d_in[0];
  const float* Wq = (const float*)d_in[1];
  const float* Wk = (const float*)d_in[2];
  const float* Wv = (const float*)d_in[3];
  const float* Wo = (const float*)d_in[4];
  float* out = (float*)d_out;
  char* ws = (char*)d_ws;

  // workspace layout (bytes), total = 128 MiB
  u16*   xb   = (u16*)(ws + 0);           // 16777216
  u16*   wqb  = (u16*)(ws + 16777216);    // 8388608
  u16*   wkb  = (u16*)(ws + 25165824);    // 2097152
  u16*   wvb  = (u16*)(ws + 27262976);    // 2097152
  u16*   wob  = (u16*)(ws + 29360128);    // 8388608
  float* cosT = (float*)(ws + 37748736);  // 8388608
  float* sinT = (float*)(ws + 46137344);  // 8388608
  float* Qtmp = (float*)(ws + 54525952);  // 33554432
  u16*   attnb= (u16*)(ws + 54525952);    // alias: Qtmp dead before attn
  float* Ktmp = (float*)(ws + 88080384);  // 8388608
  u16*   Qhp  = (u16*)(ws + 96468992);    // 16777216
  u16*   Khp  = (u16*)(ws + 113246208);   // 16777216
  u16*   Vtp  = (u16*)(ws + 130023424);   // 4194304

  cvt_all<<<18432, 256, 0, stream>>>((const float4*)x, (const float4*)Wq,
                                     (const float4*)Wk, (const float4*)Wv,
                                     (const float4*)Wo, (u16x4*)xb, (u16x4*)wqb,
                                     (u16x4*)wkb, (u16x4*)wvb, (u16x4*)wob);
  rope_table<<<8192, 256, 0, stream>>>(cosT, sinT);
  gemm_bt<0><<<dim3(16, 32), 256, 0, stream>>>(xb, wqb, Qtmp, 4096, 2048, 2048);
  gemm_bt<0><<<dim3(4, 32), 256, 0, stream>>>(xb, wkb, Ktmp, 4096, 512, 2048);
  gemm_bt<1><<<dim3(4, 32), 256, 0, stream>>>(xb, wvb, Vtp, 4096, 512, 2048);
  rope_q<<<16384, 256, 0, stream>>>((const float2*)Qtmp, cosT, sinT, Qhp);
  rope_k<<<16384, 256, 0, stream>>>((const float2*)Ktmp, cosT, sinT, Khp);
  attn_kernel<<<1024, 256, 0, stream>>>(Qhp, Khp, Vtp, attnb);
  gemm_bt<0><<<dim3(16, 32), 256, 0, stream>>>(attnb, wob, out, 4096, 2048, 2048);
}

// Round 2
// 369.520 us; speedup vs baseline: 1.7631x; 1.7631x over previous
//
#include <hip/hip_runtime.h>
#include <hip/hip_bf16.h>
#include <stdint.h>

typedef unsigned short u16;
typedef u16 u16x4 __attribute__((ext_vector_type(4)));
typedef __bf16 bf16x8 __attribute__((ext_vector_type(8)));
typedef float f32x4 __attribute__((ext_vector_type(4)));

#define DEVI __device__ __forceinline__

DEVI u16 f2b(float f) {
  __hip_bfloat16 h = __float2bfloat16(f);
  return __builtin_bit_cast(u16, h);
}

DEVI f32x4 mfma16(bf16x8 a, bf16x8 b, f32x4 c) {
  return __builtin_amdgcn_mfma_f32_16x16x32_bf16(a, b, c, 0, 0, 0);
}

DEVI void gld_lds16(const u16* g, u16* l) {
  __builtin_amdgcn_global_load_lds(
      (const __attribute__((address_space(1))) unsigned int*)g,
      (__attribute__((address_space(3))) unsigned int*)l, 16, 0, 0);
}

// ---------------- convert f32 -> bf16 for x, Wq, Wk, Wv, Wo ----------------
__global__ void cvt_all(const float4* __restrict__ x, const float4* __restrict__ wq,
                        const float4* __restrict__ wk, const float4* __restrict__ wv,
                        const float4* __restrict__ wo,
                        u16x4* __restrict__ xb, u16x4* __restrict__ wqb,
                        u16x4* __restrict__ wkb, u16x4* __restrict__ wvb,
                        u16x4* __restrict__ wob) {
  long i = (long)blockIdx.x * 256 + threadIdx.x;  // 4718592 quads total
  const float4* src; u16x4* dst; long o;
  if (i < 2097152)      { src = x;  dst = xb;  o = i; }
  else if (i < 3145728) { src = wq; dst = wqb; o = i - 2097152; }
  else if (i < 3407872) { src = wk; dst = wkb; o = i - 3145728; }
  else if (i < 3670016) { src = wv; dst = wvb; o = i - 3407872; }
  else                  { src = wo; dst = wob; o = i - 3670016; }
  float4 v = src[o];
  u16x4 r = { f2b(v.x), f2b(v.y), f2b(v.z), f2b(v.w) };
  dst[o] = r;
}

// ---------------- rope cos/sin table [S=2048][D/2=1024] ----------------
__global__ void rope_table(float* __restrict__ cosT, float* __restrict__ sinT) {
  int i = blockIdx.x * 256 + threadIdx.x;  // 2097152
  int s = i >> 10, p = i & 1023;
  float freq = exp2f((float)p * -0.012976281620653759f);
  float ang = (float)s * freq;
  float sv, cv;
  sincosf(ang, &sv, &cv);
  cosT[i] = cv;
  sinT[i] = sv;
}

// ---------------- GEMM: C[M,N] = A[M,K] * Bw[N,K]^T (bf16 in, f32 acc) -----
template <int EPI>
__global__ __launch_bounds__(256)
void gemm_bt(const u16* __restrict__ A, const u16* __restrict__ Bw,
             void* __restrict__ Cout, int M, int N, int K) {
  __shared__ __align__(16) u16 lds[2][2][4096];  // [buf][A/B][128*32]
  const int tid = threadIdx.x;
  const int lane = tid & 63;
  const int w = tid >> 6;
  const int wr = w >> 1, wc = w & 1;
  const int m0 = blockIdx.y << 7, n0 = blockIdx.x << 7;

  const int srow = tid >> 2;
  const int schunk = (tid & 3) << 3;
  const u16* ga0 = A + (size_t)(m0 + srow) * K + schunk;
  const u16* gb0 = Bw + (size_t)(n0 + srow) * K + schunk;
  const size_t rstep = (size_t)64 * K;

  f32x4 acc[4][4] = {};
  const int nk = K >> 5;
  int cur = 0;

  {
    u16* la = &lds[0][0][tid << 3];
    u16* lb = &lds[0][1][tid << 3];
    gld_lds16(ga0, la);
    gld_lds16(ga0 + rstep, la + 2048);
    gld_lds16(gb0, lb);
    gld_lds16(gb0 + rstep, lb + 2048);
  }
  __syncthreads();

  const int l15 = lane & 15;
  const int kcol = (lane >> 4) << 3;
  const int arow = ((wr << 6) + l15) << 5;
  const int brow = ((wc << 6) + l15) << 5;

  for (int kt = 0; kt < nk; ++kt) {
    if (kt + 1 < nk) {
      const u16* ga = ga0 + ((size_t)(kt + 1) << 5);
      const u16* gb = gb0 + ((size_t)(kt + 1) << 5);
      u16* la = &lds[cur ^ 1][0][tid << 3];
      u16* lb = &lds[cur ^ 1][1][tid << 3];
      gld_lds16(ga, la);
      gld_lds16(ga + rstep, la + 2048);
      gld_lds16(gb, lb);
      gld_lds16(gb + rstep, lb + 2048);
    }
    const u16* la = &lds[cur][0][0];
    const u16* lb = &lds[cur][1][0];
    bf16x8 af[4], bfr[4];
#pragma unroll
    for (int mi = 0; mi < 4; ++mi)
      af[mi] = *(const bf16x8*)&la[arow + (mi << 9) + kcol];
#pragma unroll
    for (int ni = 0; ni < 4; ++ni)
      bfr[ni] = *(const bf16x8*)&lb[brow + (ni << 9) + kcol];
#pragma unroll
    for (int mi = 0; mi < 4; ++mi)
#pragma unroll
      for (int ni = 0; ni < 4; ++ni)
        acc[mi][ni] = mfma16(af[mi], bfr[ni], acc[mi][ni]);
    __syncthreads();
    cur ^= 1;
  }

  const int crow = (lane >> 4) << 2;
  const int ccol = lane & 15;
  if (EPI == 0) {
    float* C = (float*)Cout;
#pragma unroll
    for (int mi = 0; mi < 4; ++mi) {
      int row = m0 + (wr << 6) + (mi << 4) + crow;
#pragma unroll
      for (int ni = 0; ni < 4; ++ni) {
        int col = n0 + (wc << 6) + (ni << 4) + ccol;
#pragma unroll
        for (int rr = 0; rr < 4; ++rr)
          C[(size_t)(row + rr) * N + col] = acc[mi][ni][rr];
      }
    }
  } else {
    u16* Vt = (u16*)Cout;
#pragma unroll
    for (int mi = 0; mi < 4; ++mi) {
      int sg = m0 + (wr << 6) + (mi << 4) + crow;
      int b = sg >> 11, s = sg & 2047;
#pragma unroll
      for (int ni = 0; ni < 4; ++ni) {
        int n = n0 + (wc << 6) + (ni << 4) + ccol;
        u16x4 pk = { f2b(acc[mi][ni][0]), f2b(acc[mi][ni][1]),
                     f2b(acc[mi][ni][2]), f2b(acc[mi][ni][3]) };
        *(u16x4*)&Vt[((size_t)((b << 2) + (n >> 7)) * 128 + (n & 127)) * 2048 + s] = pk;
      }
    }
  }
}

// ---------------- rope Q -----------------------------------------------
__global__ void rope_q(const float2* __restrict__ Qtmp, const float* __restrict__ cosT,
                       const float* __restrict__ sinT, u16* __restrict__ Qh) {
  int i = blockIdx.x * 256 + threadIdx.x;
  int pr = i & 1023;
  int row = i >> 10;
  int s = row & 2047, b = row >> 11;
  float2 v = Qtmp[(size_t)row * 1024 + pr];
  float c = cosT[(s << 10) + pr], sn = sinT[(s << 10) + pr];
  const float SC = 0.022097086912079608f;  // 1/sqrt(2048)
  float yr = (v.x * c - v.y * sn) * SC;
  float yi = (v.x * sn + v.y * c) * SC;
  int h = pr >> 6, hp = pr & 63;
  size_t off = ((size_t)(b * 16 + h) * 2048 + s) * 128 + hp * 2;
  unsigned pk = (unsigned)f2b(yr) | ((unsigned)f2b(yi) << 16);
  *(unsigned*)&Qh[off] = pk;
}

// ---------------- rope K -----------------------------------------------
__global__ void rope_k(const float2* __restrict__ Ktmp, const float* __restrict__ cosT,
                       const float* __restrict__ sinT, u16* __restrict__ Kh) {
  int i = blockIdx.x * 256 + threadIdx.x;
  int hp = i & 63;
  int h = (i >> 6) & 15;
  int row = i >> 10;
  int s = row & 2047, b = row >> 11;
  float2 v = Ktmp[(size_t)row * 256 + ((h >> 2) << 6) + hp];
  int p = (h << 6) + hp;
  float c = cosT[(s << 10) + p], sn = sinT[(s << 10) + p];
  float yr = v.x * c - v.y * sn;
  float yi = v.x * sn + v.y * c;
  size_t off = ((size_t)(b * 16 + h) * 2048 + s) * 128 + hp * 2;
  unsigned pk = (unsigned)f2b(yr) | ((unsigned)f2b(yi) << 16);
  *(unsigned*)&Kh[off] = pk;
}

// ---------------- flash attention (LDS-staged, swizzled) -------------------
// grid: B*NH*(S/64) blocks; block = 256 thr = 4 waves; wave owns 16 q-rows.
// KVBLK=64 keys staged in LDS (K 64x128, V 128x64), double-buffered via
// global_load_lds; XOR chunk-swizzle (chunk ^= row&7) on both tiles with
// inverse-swizzled global source (rule: both-sides-or-neither).
__global__ __launch_bounds__(256)
void attn_kernel(const u16* __restrict__ Qh, const u16* __restrict__ Kh,
                 const u16* __restrict__ Vt, u16* __restrict__ attnO) {
  __shared__ __align__(16) u16 kls[2][8192];      // [64 keys][128 hd], swizzled
  __shared__ __align__(16) u16 vls[2][8192];      // [128 hd][64 keys], swizzled
  __shared__ __align__(16) u16 plds[4][16][68];   // per-wave P transpose, padded
  const int tid = threadIdx.x, lane = tid & 63, w = tid >> 6;
  const int bid = blockIdx.x;
  const int qt = 31 - (bid & 31);                 // heavy blocks dispatch first
  const int h = (bid >> 5) & 15, b = bid >> 9;
  const int q0 = qt << 6;
  const int qbase = q0 + (w << 4);

  const u16* Qp = Qh + (size_t)(b * 16 + h) * 2048 * 128;
  const u16* Kp = Kh + (size_t)(b * 16 + h) * 2048 * 128;
  const u16* Vp = Vt + (size_t)((b << 2) + (h >> 2)) * 128 * 2048;

  const int l15 = lane & 15, lg = lane >> 4;
  const int kcol = lg << 3;
  const int sw = l15 & 7;  // row-swizzle key for fragment reads

  bf16x8 qf[4];
#pragma unroll
  for (int kb = 0; kb < 4; ++kb)
    qf[kb] = *(const bf16x8*)&Qp[(size_t)(qbase + l15) * 128 + (kb << 5) + kcol];

  // staging address precompute (per-thread, constant over tiles)
  const int kRow = tid >> 4;             // + it*16
  const int kClog0 = tid & 15;           // ^ (row&7); row&7 == (tid>>4)&7
  const int kCl = (kClog0 ^ (kRow & 7)) << 3;
  const int vRow = tid >> 3;             // + it*32
  const int vCl = ((tid & 7) ^ (vRow & 7)) << 3;

  f32x4 oacc[8] = {};
  float m[4] = {-1e30f, -1e30f, -1e30f, -1e30f};
  float lsum[4] = {0.f, 0.f, 0.f, 0.f};

  const int nt = qt + 1;
  int cur = 0;

  // prologue: stage tile 0
  {
    u16* kb_ = &kls[0][tid << 3];
    u16* vb_ = &vls[0][tid << 3];
#pragma unroll
    for (int it = 0; it < 4; ++it) {
      gld_lds16(Kp + (size_t)(kRow + it * 16) * 128 + kCl, kb_ + it * 2048);
      gld_lds16(Vp + (size_t)(vRow + it * 32) * 2048 + vCl, vb_ + it * 2048);
    }
  }
  __syncthreads();

  for (int t = 0; t < nt; ++t) {
    if (t + 1 < nt) {
      const int k1 = (t + 1) << 6;
      u16* kb_ = &kls[cur ^ 1][tid << 3];
      u16* vb_ = &vls[cur ^ 1][tid << 3];
#pragma unroll
      for (int it = 0; it < 4; ++it) {
        gld_lds16(Kp + (size_t)(k1 + kRow + it * 16) * 128 + kCl, kb_ + it * 2048);
        gld_lds16(Vp + (size_t)(vRow + it * 32) * 2048 + k1 + vCl, vb_ + it * 2048);
      }
    }

    // ---- QK^T over 64 keys ----
    const u16* kb_ = kls[cur];
    f32x4 sc[4] = {};
#pragma unroll
    for (int kq = 0; kq < 4; ++kq) {
      const u16* krow = &kb_[((kq << 4) + l15) << 7];
#pragma unroll
      for (int kb = 0; kb < 4; ++kb) {
        bf16x8 kf = *(const bf16x8*)&krow[(((kb << 2) + lg) ^ sw) << 3];
        sc[kq] = mfma16(qf[kb], kf, sc[kq]);
      }
    }

    if (t == nt - 1) {  // causal diagonal tile
#pragma unroll
      for (int kq = 0; kq < 4; ++kq) {
        int key = (kq << 4) + l15;  // relative to q0
#pragma unroll
        for (int r = 0; r < 4; ++r) {
          int qr = (w << 4) + (lg << 2) + r;
          if (key > qr) sc[kq][r] = -1e30f;
        }
      }
    }

    // ---- online softmax ----
    float rmax[4], alpha[4], rs[4];
    float p[4][4];
#pragma unroll
    for (int r = 0; r < 4; ++r)
      rmax[r] = fmaxf(fmaxf(sc[0][r], sc[1][r]), fmaxf(sc[2][r], sc[3][r]));
#pragma unroll
    for (int xm = 1; xm <= 8; xm <<= 1)
#pragma unroll
      for (int r = 0; r < 4; ++r)
        rmax[r] = fmaxf(rmax[r], __shfl_xor(rmax[r], xm));
#pragma unroll
    for (int r = 0; r < 4; ++r) {
      float nm = fmaxf(m[r], rmax[r]);
      alpha[r] = __expf(m[r] - nm);
      m[r] = nm;
      rs[r] = 0.f;
#pragma unroll
      for (int kq = 0; kq < 4; ++kq) {
        p[kq][r] = __expf(sc[kq][r] - nm);
        rs[r] += p[kq][r];
      }
    }
#pragma unroll
    for (int xm = 1; xm <= 8; xm <<= 1)
#pragma unroll
      for (int r = 0; r < 4; ++r)
        rs[r] += __shfl_xor(rs[r], xm);
#pragma unroll
    for (int r = 0; r < 4; ++r) lsum[r] = lsum[r] * alpha[r] + rs[r];
#pragma unroll
    for (int hb = 0; hb < 8; ++hb)
#pragma unroll
      for (int r = 0; r < 4; ++r)
        oacc[hb][r] *= alpha[r];

    // ---- P (acc layout) -> LDS -> A-fragment layout ----
#pragma unroll
    for (int kq = 0; kq < 4; ++kq)
#pragma unroll
      for (int r = 0; r < 4; ++r)
        plds[w][(lg << 2) + r][(kq << 4) + l15] = f2b(p[kq][r]);

    bf16x8 pa0 = *(const bf16x8*)&plds[w][l15][kcol];
    bf16x8 pa1 = *(const bf16x8*)&plds[w][l15][32 + kcol];

    // ---- PV ----
    const u16* vb_ = vls[cur];
#pragma unroll
    for (int hb = 0; hb < 8; ++hb) {
      const u16* vrow = &vb_[((hb << 4) + l15) << 6];
      bf16x8 vf0 = *(const bf16x8*)&vrow[(lg ^ sw) << 3];
      bf16x8 vf1 = *(const bf16x8*)&vrow[((4 + lg) ^ sw) << 3];
      oacc[hb] = mfma16(pa0, vf0, oacc[hb]);
      oacc[hb] = mfma16(pa1, vf1, oacc[hb]);
    }

    __syncthreads();
    cur ^= 1;
  }

  float inv[4];
#pragma unroll
  for (int r = 0; r < 4; ++r) inv[r] = 1.0f / lsum[r];
  u16* op = attnO + (size_t)(b * 2048 + qbase) * 2048 + h * 128;
#pragma unroll
  for (int hb = 0; hb < 8; ++hb)
#pragma unroll
    for (int r = 0; r < 4; ++r)
      op[(size_t)((lg << 2) + r) * 2048 + (hb << 4) + l15] = f2b(oacc[hb][r] * inv[r]);
}

// ---------------------------------------------------------------------------
extern "C" void kernel_launch(void* const* d_in, const int* in_sizes, int n_in,
                              void* d_out, int out_size, void* d_ws, size_t ws_size,
                              hipStream_t stream) {
  const float* x  = (const float*)d_in[0];
  const float* Wq = (const float*)d_in[1];
  const float* Wk = (const float*)d_in[2];
  const float* Wv = (const float*)d_in[3];
  const float* Wo = (const float*)d_in[4];
  float* out = (float*)d_out;
  char* ws = (char*)d_ws;

  u16*   xb   = (u16*)(ws + 0);
  u16*   wqb  = (u16*)(ws + 16777216);
  u16*   wkb  = (u16*)(ws + 25165824);
  u16*   wvb  = (u16*)(ws + 27262976);
  u16*   wob  = (u16*)(ws + 29360128);
  float* cosT = (float*)(ws + 37748736);
  float* sinT = (float*)(ws + 46137344);
  float* Qtmp = (float*)(ws + 54525952);
  u16*   attnb= (u16*)(ws + 54525952);
  float* Ktmp = (float*)(ws + 88080384);
  u16*   Qhp  = (u16*)(ws + 96468992);
  u16*   Khp  = (u16*)(ws + 113246208);
  u16*   Vtp  = (u16*)(ws + 130023424);

  cvt_all<<<18432, 256, 0, stream>>>((const float4*)x, (const float4*)Wq,
                                     (const float4*)Wk, (const float4*)Wv,
                                     (const float4*)Wo, (u16x4*)xb, (u16x4*)wqb,
                                     (u16x4*)wkb, (u16x4*)wvb, (u16x4*)wob);
  rope_table<<<8192, 256, 0, stream>>>(cosT, sinT);
  gemm_bt<0><<<dim3(16, 32), 256, 0, stream>>>(xb, wqb, Qtmp, 4096, 2048, 2048);
  gemm_bt<0><<<dim3(4, 32), 256, 0, stream>>>(xb, wkb, Ktmp, 4096, 512, 2048);
  gemm_bt<1><<<dim3(4, 32), 256, 0, stream>>>(xb, wvb, Vtp, 4096, 512, 2048);
  rope_q<<<16384, 256, 0, stream>>>((const float2*)Qtmp, cosT, sinT, Qhp);
  rope_k<<<16384, 256, 0, stream>>>((const float2*)Ktmp, cosT, sinT, Khp);
  attn_kernel<<<1024, 256, 0, stream>>>(Qhp, Khp, Vtp, attnb);
  gemm_bt<0><<<dim3(16, 32), 256, 0, stream>>>(attnb, wob, out, 4096, 2048, 2048);
}

// Round 3
// 276.967 us; speedup vs baseline: 2.3522x; 1.3342x over previous
//
#include <hip/hip_runtime.h>
#include <hip/hip_bf16.h>
#include <stdint.h>

typedef unsigned short u16;
typedef u16 u16x4 __attribute__((ext_vector_type(4)));
typedef unsigned u32x4 __attribute__((ext_vector_type(4)));
typedef __bf16 bf16x8 __attribute__((ext_vector_type(8)));
typedef float f32x4 __attribute__((ext_vector_type(4)));
typedef float f32x16 __attribute__((ext_vector_type(16)));

#define DEVI __device__ __forceinline__

DEVI u16 f2b(float f) {
  __hip_bfloat16 h = __float2bfloat16(f);
  return __builtin_bit_cast(u16, h);
}

DEVI unsigned pk2(float lo, float hi) {
  return (unsigned)f2b(lo) | ((unsigned)f2b(hi) << 16);
}

DEVI f32x4 mfma16(bf16x8 a, bf16x8 b, f32x4 c) {
  return __builtin_amdgcn_mfma_f32_16x16x32_bf16(a, b, c, 0, 0, 0);
}

DEVI f32x16 mfma32(bf16x8 a, bf16x8 b, f32x16 c) {
  return __builtin_amdgcn_mfma_f32_32x32x16_bf16(a, b, c, 0, 0, 0);
}

DEVI void gld_lds16(const u16* g, u16* l) {
  __builtin_amdgcn_global_load_lds(
      (const __attribute__((address_space(1))) unsigned int*)g,
      (__attribute__((address_space(3))) unsigned int*)l, 16, 0, 0);
}

// ---------------- convert f32 -> bf16 for x, Wq, Wk, Wv, Wo ----------------
__global__ void cvt_all(const float4* __restrict__ x, const float4* __restrict__ wq,
                        const float4* __restrict__ wk, const float4* __restrict__ wv,
                        const float4* __restrict__ wo,
                        u16x4* __restrict__ xb, u16x4* __restrict__ wqb,
                        u16x4* __restrict__ wkb, u16x4* __restrict__ wvb,
                        u16x4* __restrict__ wob) {
  long i = (long)blockIdx.x * 256 + threadIdx.x;  // 4718592 quads total
  const float4* src; u16x4* dst; long o;
  if (i < 2097152)      { src = x;  dst = xb;  o = i; }
  else if (i < 3145728) { src = wq; dst = wqb; o = i - 2097152; }
  else if (i < 3407872) { src = wk; dst = wkb; o = i - 3145728; }
  else if (i < 3670016) { src = wv; dst = wvb; o = i - 3407872; }
  else                  { src = wo; dst = wob; o = i - 3670016; }
  float4 v = src[o];
  u16x4 r = { f2b(v.x), f2b(v.y), f2b(v.z), f2b(v.w) };
  dst[o] = r;
}

// ---------------- rope cos/sin table [S=2048][D/2=1024] ----------------
__global__ void rope_table(float* __restrict__ cosT, float* __restrict__ sinT) {
  int i = blockIdx.x * 256 + threadIdx.x;  // 2097152
  int s = i >> 10, p = i & 1023;
  float freq = exp2f((float)p * -0.012976281620653759f);
  float ang = (float)s * freq;
  float sv, cv;
  sincosf(ang, &sv, &cv);
  cosT[i] = cv;
  sinT[i] = sv;
}

// ---------------- GEMM: C[M,N] = A[M,K] * Bw[N,K]^T (bf16 in, f32 acc) -----
template <int EPI>
__global__ __launch_bounds__(256)
void gemm_bt(const u16* __restrict__ A, const u16* __restrict__ Bw,
             void* __restrict__ Cout, int M, int N, int K) {
  __shared__ __align__(16) u16 lds[2][2][4096];  // [buf][A/B][128*32]
  const int tid = threadIdx.x;
  const int lane = tid & 63;
  const int w = tid >> 6;
  const int wr = w >> 1, wc = w & 1;
  const int m0 = blockIdx.y << 7, n0 = blockIdx.x << 7;

  const int srow = tid >> 2;
  const int schunk = (tid & 3) << 3;
  const u16* ga0 = A + (size_t)(m0 + srow) * K + schunk;
  const u16* gb0 = Bw + (size_t)(n0 + srow) * K + schunk;
  const size_t rstep = (size_t)64 * K;

  f32x4 acc[4][4] = {};
  const int nk = K >> 5;
  int cur = 0;

  {
    u16* la = &lds[0][0][tid << 3];
    u16* lb = &lds[0][1][tid << 3];
    gld_lds16(ga0, la);
    gld_lds16(ga0 + rstep, la + 2048);
    gld_lds16(gb0, lb);
    gld_lds16(gb0 + rstep, lb + 2048);
  }
  __syncthreads();

  const int l15 = lane & 15;
  const int kcol = (lane >> 4) << 3;
  const int arow = ((wr << 6) + l15) << 5;
  const int brow = ((wc << 6) + l15) << 5;

  for (int kt = 0; kt < nk; ++kt) {
    if (kt + 1 < nk) {
      const u16* ga = ga0 + ((size_t)(kt + 1) << 5);
      const u16* gb = gb0 + ((size_t)(kt + 1) << 5);
      u16* la = &lds[cur ^ 1][0][tid << 3];
      u16* lb = &lds[cur ^ 1][1][tid << 3];
      gld_lds16(ga, la);
      gld_lds16(ga + rstep, la + 2048);
      gld_lds16(gb, lb);
      gld_lds16(gb + rstep, lb + 2048);
    }
    const u16* la = &lds[cur][0][0];
    const u16* lb = &lds[cur][1][0];
    bf16x8 af[4], bfr[4];
#pragma unroll
    for (int mi = 0; mi < 4; ++mi)
      af[mi] = *(const bf16x8*)&la[arow + (mi << 9) + kcol];
#pragma unroll
    for (int ni = 0; ni < 4; ++ni)
      bfr[ni] = *(const bf16x8*)&lb[brow + (ni << 9) + kcol];
#pragma unroll
    for (int mi = 0; mi < 4; ++mi)
#pragma unroll
      for (int ni = 0; ni < 4; ++ni)
        acc[mi][ni] = mfma16(af[mi], bfr[ni], acc[mi][ni]);
    __syncthreads();
    cur ^= 1;
  }

  const int crow = (lane >> 4) << 2;
  const int ccol = lane & 15;
  if (EPI == 0) {
    float* C = (float*)Cout;
#pragma unroll
    for (int mi = 0; mi < 4; ++mi) {
      int row = m0 + (wr << 6) + (mi << 4) + crow;
#pragma unroll
      for (int ni = 0; ni < 4; ++ni) {
        int col = n0 + (wc << 6) + (ni << 4) + ccol;
#pragma unroll
        for (int rr = 0; rr < 4; ++rr)
          C[(size_t)(row + rr) * N + col] = acc[mi][ni][rr];
      }
    }
  } else {
    u16* Vt = (u16*)Cout;
#pragma unroll
    for (int mi = 0; mi < 4; ++mi) {
      int sg = m0 + (wr << 6) + (mi << 4) + crow;
      int b = sg >> 11, s = sg & 2047;
#pragma unroll
      for (int ni = 0; ni < 4; ++ni) {
        int n = n0 + (wc << 6) + (ni << 4) + ccol;
        u16x4 pk = { f2b(acc[mi][ni][0]), f2b(acc[mi][ni][1]),
                     f2b(acc[mi][ni][2]), f2b(acc[mi][ni][3]) };
        *(u16x4*)&Vt[((size_t)((b << 2) + (n >> 7)) * 128 + (n & 127)) * 2048 + s] = pk;
      }
    }
  }
}

// ---------------- rope Q -----------------------------------------------
__global__ void rope_q(const float2* __restrict__ Qtmp, const float* __restrict__ cosT,
                       const float* __restrict__ sinT, u16* __restrict__ Qh) {
  int i = blockIdx.x * 256 + threadIdx.x;
  int pr = i & 1023;
  int row = i >> 10;
  int s = row & 2047, b = row >> 11;
  float2 v = Qtmp[(size_t)row * 1024 + pr];
  float c = cosT[(s << 10) + pr], sn = sinT[(s << 10) + pr];
  const float SC = 0.022097086912079608f;  // 1/sqrt(2048)
  float yr = (v.x * c - v.y * sn) * SC;
  float yi = (v.x * sn + v.y * c) * SC;
  int h = pr >> 6, hp = pr & 63;
  size_t off = ((size_t)(b * 16 + h) * 2048 + s) * 128 + hp * 2;
  unsigned pk = (unsigned)f2b(yr) | ((unsigned)f2b(yi) << 16);
  *(unsigned*)&Qh[off] = pk;
}

// ---------------- rope K -----------------------------------------------
__global__ void rope_k(const float2* __restrict__ Ktmp, const float* __restrict__ cosT,
                       const float* __restrict__ sinT, u16* __restrict__ Kh) {
  int i = blockIdx.x * 256 + threadIdx.x;
  int hp = i & 63;
  int h = (i >> 6) & 15;
  int row = i >> 10;
  int s = row & 2047, b = row >> 11;
  float2 v = Ktmp[(size_t)row * 256 + ((h >> 2) << 6) + hp];
  int p = (h << 6) + hp;
  float c = cosT[(s << 10) + p], sn = sinT[(s << 10) + p];
  float yr = v.x * c - v.y * sn;
  float yi = v.x * sn + v.y * c;
  size_t off = ((size_t)(b * 16 + h) * 2048 + s) * 128 + hp * 2;
  unsigned pk = (unsigned)f2b(yr) | ((unsigned)f2b(yi) << 16);
  *(unsigned*)&Kh[off] = pk;
}

// ---------------- flash attention: swapped-operand 32x32, in-reg softmax ---
// grid: 512 blocks (qt complement-paired heavy-first), 4 waves x 32 q-rows.
// S^T = mfma(K, Q): lane owns q = lane&31; softmax fully lane-local.
// O^T = mfma(V^T, P^T): P frags built via pk2 + v_permlane32_swap_b32.
__global__ __launch_bounds__(256, 2)
void attn_kernel(const u16* __restrict__ Qh, const u16* __restrict__ Kh,
                 const u16* __restrict__ Vt, u16* __restrict__ attnO) {
  __shared__ __align__(16) u16 kls[2][8192];  // [64 keys][128 hd], swizzled
  __shared__ __align__(16) u16 vls[2][8192];  // [128 hd][64 keys], swizzled
  const int tid = threadIdx.x, lane = tid & 63, w = tid >> 6;
  const int bid = blockIdx.x;
  const int r_ = bid & 15;
  const int qt = (bid & 256) ? r_ : 15 - r_;   // complement pairing across halves
  const int bh = (bid >> 4) & 31;
  const int h = bh & 15, b = bh >> 4;

  const int qi = lane & 31, hi = lane >> 5;
  const int q0 = qt * 128 + w * 32;
  const int qabs = q0 + qi;

  const u16* Qp = Qh + (size_t)(b * 16 + h) * 2048 * 128;
  const u16* Kp = Kh + (size_t)(b * 16 + h) * 2048 * 128;
  const u16* Vp = Vt + (size_t)((b << 2) + (h >> 2)) * 128 * 2048;

  // Q as B-fragment: qf[kc] = Q[qabs][kc*16 + hi*8 .. +7]
  bf16x8 qf[8];
#pragma unroll
  for (int kc = 0; kc < 8; ++kc)
    qf[kc] = *(const bf16x8*)&Qp[(size_t)qabs * 128 + kc * 16 + hi * 8];

  // staging (same proven pattern/swizzle as round-2)
  const int kRow = tid >> 4;
  const int kCl = ((tid & 15) ^ (kRow & 7)) << 3;
  const int vRow = tid >> 3;
  const int vCl = ((tid & 7) ^ (vRow & 7)) << 3;

  f32x16 ot[4] = {};
  float mrow = -1e30f, lsum = 0.f;

  const int nt = 2 * qt + 2;                  // tiles for the block
  const int nt_w = ((q0 + 31) >> 6) + 1;      // tiles this wave computes
  int cur = 0;
  const int swz = qi & 7;

  {
    u16* kb_ = &kls[0][tid << 3];
    u16* vb_ = &vls[0][tid << 3];
#pragma unroll
    for (int it = 0; it < 4; ++it) {
      gld_lds16(Kp + (size_t)(kRow + it * 16) * 128 + kCl, kb_ + it * 2048);
      gld_lds16(Vp + (size_t)(vRow + it * 32) * 2048 + vCl, vb_ + it * 2048);
    }
  }
  __syncthreads();

  for (int t = 0; t < nt; ++t) {
    if (t + 1 < nt) {
      const int k1 = (t + 1) << 6;
      u16* kb_ = &kls[cur ^ 1][tid << 3];
      u16* vb_ = &vls[cur ^ 1][tid << 3];
#pragma unroll
      for (int it = 0; it < 4; ++it) {
        gld_lds16(Kp + (size_t)(k1 + kRow + it * 16) * 128 + kCl, kb_ + it * 2048);
        gld_lds16(Vp + (size_t)(vRow + it * 32) * 2048 + k1 + vCl, vb_ + it * 2048);
      }
    }
    if (t < nt_w) {
      const u16* kb_ = kls[cur];
      f32x16 st0 = {}, st1 = {};
      __builtin_amdgcn_s_setprio(1);
#pragma unroll
      for (int kc = 0; kc < 8; ++kc) {
        bf16x8 kf0 = *(const bf16x8*)&kb_[(qi << 7) + ((((kc << 1) + hi) ^ swz) << 3)];
        bf16x8 kf1 = *(const bf16x8*)&kb_[((32 + qi) << 7) + ((((kc << 1) + hi) ^ swz) << 3)];
        st0 = mfma32(kf0, qf[kc], st0);
        st1 = mfma32(kf1, qf[kc], st1);
      }
      __builtin_amdgcn_s_setprio(0);

      if (t == nt_w - 1) {  // only the last computed tile crosses the diagonal
        const int kb0 = t << 6;
#pragma unroll
        for (int reg = 0; reg < 16; ++reg) {
          int kofs = (reg & 3) + ((reg >> 2) << 3) + (hi << 2);
          if (kb0 + kofs > qabs) st0[reg] = -1e30f;
          if (kb0 + 32 + kofs > qabs) st1[reg] = -1e30f;
        }
      }

      // row max: 32 in-lane + cross-half exchange
      float tmax = st0[0];
#pragma unroll
      for (int reg = 1; reg < 16; ++reg) tmax = fmaxf(tmax, st0[reg]);
#pragma unroll
      for (int reg = 0; reg < 16; ++reg) tmax = fmaxf(tmax, st1[reg]);
      tmax = fmaxf(tmax, __shfl_xor(tmax, 32));

      // defer-max (T13): rescale only when max grows past threshold
      if (__any(tmax - mrow > 8.f)) {
        float nm = fmaxf(mrow, tmax);
        float al = __expf(mrow - nm);
        mrow = nm;
        lsum *= al;
#pragma unroll
        for (int db = 0; db < 4; ++db)
#pragma unroll
          for (int reg = 0; reg < 16; ++reg) ot[db][reg] *= al;
      }

      float psum = 0.f;
#pragma unroll
      for (int reg = 0; reg < 16; ++reg) { st0[reg] = __expf(st0[reg] - mrow); psum += st0[reg]; }
#pragma unroll
      for (int reg = 0; reg < 16; ++reg) { st1[reg] = __expf(st1[reg] - mrow); psum += st1[reg]; }
      psum += __shfl_xor(psum, 32);
      lsum += psum;

      // P -> bf16 B-frags: pack pairs, permlane32_swap across hi-halves
      bf16x8 pfrag[4];
#pragma unroll
      for (int sub = 0; sub < 2; ++sub) {
        f32x16 S = sub ? st1 : st0;
#pragma unroll
        for (int bbp = 0; bbp < 2; ++bbp) {
          unsigned x0 = pk2(S[8 * bbp + 0], S[8 * bbp + 1]);
          unsigned x1 = pk2(S[8 * bbp + 2], S[8 * bbp + 3]);
          unsigned y0 = pk2(S[8 * bbp + 4], S[8 * bbp + 5]);
          unsigned y1 = pk2(S[8 * bbp + 6], S[8 * bbp + 7]);
          asm("v_permlane32_swap_b32 %0, %1" : "+v"(x0), "+v"(y0));
          asm("v_permlane32_swap_b32 %0, %1" : "+v"(x1), "+v"(y1));
          u32x4 uw = { x0, x1, y0, y1 };
          pfrag[2 * sub + bbp] = __builtin_bit_cast(bf16x8, uw);
        }
      }

      // O^T += V^T * P^T
      const u16* vb_ = vls[cur];
      __builtin_amdgcn_s_setprio(1);
#pragma unroll
      for (int db = 0; db < 4; ++db) {
        const u16* vr = &vb_[((db << 5) + qi) << 6];
#pragma unroll
        for (int ks = 0; ks < 4; ++ks) {
          bf16x8 vf = *(const bf16x8*)&vr[(((ks << 1) + hi) ^ swz) << 3];
          ot[db] = mfma32(vf, pfrag[ks], ot[db]);
        }
      }
      __builtin_amdgcn_s_setprio(0);
    }
    __syncthreads();
    cur ^= 1;
  }

  float inv = 1.f / lsum;
  u16* rowp = attnO + (size_t)(b * 2048 + qabs) * 2048 + h * 128 + (hi << 2);
#pragma unroll
  for (int db = 0; db < 4; ++db)
#pragma unroll
    for (int mg = 0; mg < 4; ++mg) {
      u16x4 pkv = { f2b(ot[db][4 * mg + 0] * inv), f2b(ot[db][4 * mg + 1] * inv),
                    f2b(ot[db][4 * mg + 2] * inv), f2b(ot[db][4 * mg + 3] * inv) };
      *(u16x4*)&rowp[(db << 5) + (mg << 3)] = pkv;
    }
}

// ---------------------------------------------------------------------------
extern "C" void kernel_launch(void* const* d_in, const int* in_sizes, int n_in,
                              void* d_out, int out_size, void* d_ws, size_t ws_size,
                              hipStream_t stream) {
  const float* x  = (const float*)d_in[0];
  const float* Wq = (const float*)d_in[1];
  const float* Wk = (const float*)d_in[2];
  const float* Wv = (const float*)d_in[3];
  const float* Wo = (const float*)d_in[4];
  float* out = (float*)d_out;
  char* ws = (char*)d_ws;

  u16*   xb   = (u16*)(ws + 0);
  u16*   wqb  = (u16*)(ws + 16777216);
  u16*   wkb  = (u16*)(ws + 25165824);
  u16*   wvb  = (u16*)(ws + 27262976);
  u16*   wob  = (u16*)(ws + 29360128);
  float* cosT = (float*)(ws + 37748736);
  float* sinT = (float*)(ws + 46137344);
  float* Qtmp = (float*)(ws + 54525952);
  u16*   attnb= (u16*)(ws + 54525952);   // alias: Qtmp dead before attn
  float* Ktmp = (float*)(ws + 88080384);
  u16*   Qhp  = (u16*)(ws + 96468992);
  u16*   Khp  = (u16*)(ws + 113246208);
  u16*   Vtp  = (u16*)(ws + 130023424);

  cvt_all<<<18432, 256, 0, stream>>>((const float4*)x, (const float4*)Wq,
                                     (const float4*)Wk, (const float4*)Wv,
                                     (const float4*)Wo, (u16x4*)xb, (u16x4*)wqb,
                                     (u16x4*)wkb, (u16x4*)wvb, (u16x4*)wob);
  rope_table<<<8192, 256, 0, stream>>>(cosT, sinT);
  gemm_bt<0><<<dim3(16, 32), 256, 0, stream>>>(xb, wqb, Qtmp, 4096, 2048, 2048);
  gemm_bt<0><<<dim3(4, 32), 256, 0, stream>>>(xb, wkb, Ktmp, 4096, 512, 2048);
  gemm_bt<1><<<dim3(4, 32), 256, 0, stream>>>(xb, wvb, Vtp, 4096, 512, 2048);
  rope_q<<<16384, 256, 0, stream>>>((const float2*)Qtmp, cosT, sinT, Qhp);
  rope_k<<<16384, 256, 0, stream>>>((const float2*)Ktmp, cosT, sinT, Khp);
  attn_kernel<<<512, 256, 0, stream>>>(Qhp, Khp, Vtp, attnb);
  gemm_bt<0><<<dim3(16, 32), 256, 0, stream>>>(attnb, wob, out, 4096, 2048, 2048);
}

// Round 4
// 229.369 us; speedup vs baseline: 2.8403x; 1.2075x over previous
//
#include <hip/hip_runtime.h>
#include <hip/hip_bf16.h>
#include <stdint.h>

typedef unsigned short u16;
typedef u16 u16x4 __attribute__((ext_vector_type(4)));
typedef unsigned u32x4 __attribute__((ext_vector_type(4)));
typedef __bf16 bf16x8 __attribute__((ext_vector_type(8)));
typedef float f32x4 __attribute__((ext_vector_type(4)));
typedef float f32x16 __attribute__((ext_vector_type(16)));

#define DEVI __device__ __forceinline__

DEVI u16 f2b(float f) {
  __hip_bfloat16 h = __float2bfloat16(f);
  return __builtin_bit_cast(u16, h);
}

DEVI unsigned pk2(float lo, float hi) {
  return (unsigned)f2b(lo) | ((unsigned)f2b(hi) << 16);
}

DEVI f32x4 mfma16(bf16x8 a, bf16x8 b, f32x4 c) {
  return __builtin_amdgcn_mfma_f32_16x16x32_bf16(a, b, c, 0, 0, 0);
}

DEVI f32x16 mfma32(bf16x8 a, bf16x8 b, f32x16 c) {
  return __builtin_amdgcn_mfma_f32_32x32x16_bf16(a, b, c, 0, 0, 0);
}

DEVI void gld_lds16(const u16* g, u16* l) {
  __builtin_amdgcn_global_load_lds(
      (const __attribute__((address_space(1))) unsigned int*)g,
      (__attribute__((address_space(3))) unsigned int*)l, 16, 0, 0);
}

// ---------------- convert f32 -> bf16 for x, Wq, Wk, Wv, Wo ----------------
__global__ void cvt_all(const float4* __restrict__ x, const float4* __restrict__ wq,
                        const float4* __restrict__ wk, const float4* __restrict__ wv,
                        const float4* __restrict__ wo,
                        u16x4* __restrict__ xb, u16x4* __restrict__ wqb,
                        u16x4* __restrict__ wkb, u16x4* __restrict__ wvb,
                        u16x4* __restrict__ wob) {
  long i = (long)blockIdx.x * 256 + threadIdx.x;  // 4718592 quads total
  const float4* src; u16x4* dst; long o;
  if (i < 2097152)      { src = x;  dst = xb;  o = i; }
  else if (i < 3145728) { src = wq; dst = wqb; o = i - 2097152; }
  else if (i < 3407872) { src = wk; dst = wkb; o = i - 3145728; }
  else if (i < 3670016) { src = wv; dst = wvb; o = i - 3407872; }
  else                  { src = wo; dst = wob; o = i - 3670016; }
  float4 v = src[o];
  u16x4 r = { f2b(v.x), f2b(v.y), f2b(v.z), f2b(v.w) };
  dst[o] = r;
}

// ---------------- rope cos/sin table [S=2048][D/2=1024] ----------------
__global__ void rope_table(float* __restrict__ cosT, float* __restrict__ sinT) {
  int i = blockIdx.x * 256 + threadIdx.x;  // 2097152
  int s = i >> 10, p = i & 1023;
  float freq = exp2f((float)p * -0.012976281620653759f);
  float ang = (float)s * freq;
  float sv, cv;
  __sincosf(ang, &sv, &cv);
  cosT[i] = cv;
  sinT[i] = sv;
}

// ---------------- fused QKV GEMM: [4096 x 3072] over K=2048 ---------------
// bx 0..15: Q cols -> Qtmp f32; bx 16..19: K cols -> Ktmp f32;
// bx 20..23: V cols -> Vt transposed bf16.
__global__ __launch_bounds__(256)
void gemm_qkv(const u16* __restrict__ A, const u16* __restrict__ wq,
              const u16* __restrict__ wk, const u16* __restrict__ wv,
              float* __restrict__ Qtmp, float* __restrict__ Ktmp,
              u16* __restrict__ Vtp) {
  __shared__ __align__(16) u16 lds[2][2][4096];
  const int tid = threadIdx.x;
  const int lane = tid & 63;
  const int w = tid >> 6;
  const int wr = w >> 1, wc = w & 1;
  const int bx = blockIdx.x;
  const int m0 = blockIdx.y << 7, n0 = bx << 7;
  const int K = 2048;

  const u16* Bw;
  int mode;
  if (bx < 16)      { Bw = wq + (size_t)n0 * K;          mode = 0; }
  else if (bx < 20) { Bw = wk + (size_t)(n0 - 2048) * K; mode = 1; }
  else              { Bw = wv + (size_t)(n0 - 2560) * K; mode = 2; }

  const int srow = tid >> 2;
  const int schunk = (tid & 3) << 3;
  const u16* ga0 = A + (size_t)(m0 + srow) * K + schunk;
  const u16* gb0 = Bw + (size_t)srow * K + schunk;
  const size_t rstep = (size_t)64 * K;

  f32x4 acc[4][4] = {};
  const int nk = K >> 5;
  int cur = 0;

  {
    u16* la = &lds[0][0][tid << 3];
    u16* lb = &lds[0][1][tid << 3];
    gld_lds16(ga0, la);
    gld_lds16(ga0 + rstep, la + 2048);
    gld_lds16(gb0, lb);
    gld_lds16(gb0 + rstep, lb + 2048);
  }
  __syncthreads();

  const int l15 = lane & 15;
  const int kcol = (lane >> 4) << 3;
  const int arow = ((wr << 6) + l15) << 5;
  const int brow = ((wc << 6) + l15) << 5;

  for (int kt = 0; kt < nk; ++kt) {
    if (kt + 1 < nk) {
      const u16* ga = ga0 + ((size_t)(kt + 1) << 5);
      const u16* gb = gb0 + ((size_t)(kt + 1) << 5);
      u16* la = &lds[cur ^ 1][0][tid << 3];
      u16* lb = &lds[cur ^ 1][1][tid << 3];
      gld_lds16(ga, la);
      gld_lds16(ga + rstep, la + 2048);
      gld_lds16(gb, lb);
      gld_lds16(gb + rstep, lb + 2048);
    }
    const u16* la = &lds[cur][0][0];
    const u16* lb = &lds[cur][1][0];
    bf16x8 af[4], bfr[4];
#pragma unroll
    for (int mi = 0; mi < 4; ++mi)
      af[mi] = *(const bf16x8*)&la[arow + (mi << 9) + kcol];
#pragma unroll
    for (int ni = 0; ni < 4; ++ni)
      bfr[ni] = *(const bf16x8*)&lb[brow + (ni << 9) + kcol];
#pragma unroll
    for (int mi = 0; mi < 4; ++mi)
#pragma unroll
      for (int ni = 0; ni < 4; ++ni)
        acc[mi][ni] = mfma16(af[mi], bfr[ni], acc[mi][ni]);
    __syncthreads();
    cur ^= 1;
  }

  const int crow = (lane >> 4) << 2;
  const int ccol = lane & 15;
  if (mode == 0) {
#pragma unroll
    for (int mi = 0; mi < 4; ++mi) {
      int row = m0 + (wr << 6) + (mi << 4) + crow;
#pragma unroll
      for (int ni = 0; ni < 4; ++ni) {
        int col = n0 + (wc << 6) + (ni << 4) + ccol;
#pragma unroll
        for (int rr = 0; rr < 4; ++rr)
          Qtmp[(size_t)(row + rr) * 2048 + col] = acc[mi][ni][rr];
      }
    }
  } else if (mode == 1) {
#pragma unroll
    for (int mi = 0; mi < 4; ++mi) {
      int row = m0 + (wr << 6) + (mi << 4) + crow;
#pragma unroll
      for (int ni = 0; ni < 4; ++ni) {
        int col = (n0 - 2048) + (wc << 6) + (ni << 4) + ccol;
#pragma unroll
        for (int rr = 0; rr < 4; ++rr)
          Ktmp[(size_t)(row + rr) * 512 + col] = acc[mi][ni][rr];
      }
    }
  } else {
#pragma unroll
    for (int mi = 0; mi < 4; ++mi) {
      int sg = m0 + (wr << 6) + (mi << 4) + crow;
      int b = sg >> 11, s = sg & 2047;
#pragma unroll
      for (int ni = 0; ni < 4; ++ni) {
        int n = (n0 - 2560) + (wc << 6) + (ni << 4) + ccol;
        u16x4 pk = { f2b(acc[mi][ni][0]), f2b(acc[mi][ni][1]),
                     f2b(acc[mi][ni][2]), f2b(acc[mi][ni][3]) };
        *(u16x4*)&Vtp[((size_t)((b << 2) + (n >> 7)) * 128 + (n & 127)) * 2048 + s] = pk;
      }
    }
  }
}

// ---------------- GEMM: C[M,N] = A[M,K] * Bw[N,K]^T (O projection) --------
__global__ __launch_bounds__(256)
void gemm_bt(const u16* __restrict__ A, const u16* __restrict__ Bw,
             float* __restrict__ C, int M, int N, int K) {
  __shared__ __align__(16) u16 lds[2][2][4096];
  const int tid = threadIdx.x;
  const int lane = tid & 63;
  const int w = tid >> 6;
  const int wr = w >> 1, wc = w & 1;
  const int m0 = blockIdx.y << 7, n0 = blockIdx.x << 7;

  const int srow = tid >> 2;
  const int schunk = (tid & 3) << 3;
  const u16* ga0 = A + (size_t)(m0 + srow) * K + schunk;
  const u16* gb0 = Bw + (size_t)(n0 + srow) * K + schunk;
  const size_t rstep = (size_t)64 * K;

  f32x4 acc[4][4] = {};
  const int nk = K >> 5;
  int cur = 0;

  {
    u16* la = &lds[0][0][tid << 3];
    u16* lb = &lds[0][1][tid << 3];
    gld_lds16(ga0, la);
    gld_lds16(ga0 + rstep, la + 2048);
    gld_lds16(gb0, lb);
    gld_lds16(gb0 + rstep, lb + 2048);
  }
  __syncthreads();

  const int l15 = lane & 15;
  const int kcol = (lane >> 4) << 3;
  const int arow = ((wr << 6) + l15) << 5;
  const int brow = ((wc << 6) + l15) << 5;

  for (int kt = 0; kt < nk; ++kt) {
    if (kt + 1 < nk) {
      const u16* ga = ga0 + ((size_t)(kt + 1) << 5);
      const u16* gb = gb0 + ((size_t)(kt + 1) << 5);
      u16* la = &lds[cur ^ 1][0][tid << 3];
      u16* lb = &lds[cur ^ 1][1][tid << 3];
      gld_lds16(ga, la);
      gld_lds16(ga + rstep, la + 2048);
      gld_lds16(gb, lb);
      gld_lds16(gb + rstep, lb + 2048);
    }
    const u16* la = &lds[cur][0][0];
    const u16* lb = &lds[cur][1][0];
    bf16x8 af[4], bfr[4];
#pragma unroll
    for (int mi = 0; mi < 4; ++mi)
      af[mi] = *(const bf16x8*)&la[arow + (mi << 9) + kcol];
#pragma unroll
    for (int ni = 0; ni < 4; ++ni)
      bfr[ni] = *(const bf16x8*)&lb[brow + (ni << 9) + kcol];
#pragma unroll
    for (int mi = 0; mi < 4; ++mi)
#pragma unroll
      for (int ni = 0; ni < 4; ++ni)
        acc[mi][ni] = mfma16(af[mi], bfr[ni], acc[mi][ni]);
    __syncthreads();
    cur ^= 1;
  }

  const int crow = (lane >> 4) << 2;
  const int ccol = lane & 15;
#pragma unroll
  for (int mi = 0; mi < 4; ++mi) {
    int row = m0 + (wr << 6) + (mi << 4) + crow;
#pragma unroll
    for (int ni = 0; ni < 4; ++ni) {
      int col = n0 + (wc << 6) + (ni << 4) + ccol;
#pragma unroll
      for (int rr = 0; rr < 4; ++rr)
        C[(size_t)(row + rr) * N + col] = acc[mi][ni][rr];
    }
  }
}

// ---------------- rope Q (folds score scale AND log2e for exp2 softmax) ----
__global__ void rope_q(const float2* __restrict__ Qtmp, const float* __restrict__ cosT,
                       const float* __restrict__ sinT, u16* __restrict__ Qh) {
  int i = blockIdx.x * 256 + threadIdx.x;
  int pr = i & 1023;
  int row = i >> 10;
  int s = row & 2047, b = row >> 11;
  float2 v = Qtmp[(size_t)row * 1024 + pr];
  float c = cosT[(s << 10) + pr], sn = sinT[(s << 10) + pr];
  const float SC = 0.022097086912079608f * 1.4426950408889634f;  // /sqrt(2048)*log2e
  float yr = (v.x * c - v.y * sn) * SC;
  float yi = (v.x * sn + v.y * c) * SC;
  int h = pr >> 6, hp = pr & 63;
  size_t off = ((size_t)(b * 16 + h) * 2048 + s) * 128 + hp * 2;
  unsigned pk = (unsigned)f2b(yr) | ((unsigned)f2b(yi) << 16);
  *(unsigned*)&Qh[off] = pk;
}

// ---------------- rope K -----------------------------------------------
__global__ void rope_k(const float2* __restrict__ Ktmp, const float* __restrict__ cosT,
                       const float* __restrict__ sinT, u16* __restrict__ Kh) {
  int i = blockIdx.x * 256 + threadIdx.x;
  int hp = i & 63;
  int h = (i >> 6) & 15;
  int row = i >> 10;
  int s = row & 2047, b = row >> 11;
  float2 v = Ktmp[(size_t)row * 256 + ((h >> 2) << 6) + hp];
  int p = (h << 6) + hp;
  float c = cosT[(s << 10) + p], sn = sinT[(s << 10) + p];
  float yr = v.x * c - v.y * sn;
  float yi = v.x * sn + v.y * c;
  size_t off = ((size_t)(b * 16 + h) * 2048 + s) * 128 + hp * 2;
  unsigned pk = (unsigned)f2b(yr) | ((unsigned)f2b(yi) << 16);
  *(unsigned*)&Kh[off] = pk;
}

// ---------------- flash attention: counted-vmcnt 3-buffer pipeline ---------
// KVBLK=32; 512 blocks, 4 waves x 32 q-rows; XCD-chunked bh; complement-
// paired qt per CU. One raw s_barrier/tile; vmcnt(4) keeps 2-deep prefetch.
__global__ __launch_bounds__(256, 2)
void attn_kernel(const u16* __restrict__ Qh, const u16* __restrict__ Kh,
                 const u16* __restrict__ Vt, u16* __restrict__ attnO) {
  __shared__ __align__(16) u16 lds[3][8192];  // per buf: K[0:4096] V[4096:8192]
  const int tid = threadIdx.x, lane = tid & 63, w = tid >> 6;
  const int bid = blockIdx.x;
  const int x = bid & 7, j = bid >> 3;
  const int half = j >> 5, jj = j & 31;
  const int bh = (x << 2) + (jj >> 4) + (half << 1);  // 4 bh per XCD
  const int r = jj & 15;
  const int qt = half ? r : 15 - r;                    // CU pair sums to 15
  const int h = bh & 15, b = bh >> 4;

  const int qi = lane & 31, hi = lane >> 5;
  const int q0 = (qt << 7) + (w << 5);
  const int qabs = q0 + qi;

  const u16* Qp = Qh + (size_t)(b * 16 + h) * 262144;
  const u16* Kp = Kh + (size_t)(b * 16 + h) * 262144;
  const u16* Vp = Vt + (size_t)((b << 2) + (h >> 2)) * 262144;

  bf16x8 qf[8];
#pragma unroll
  for (int kc = 0; kc < 8; ++kc)
    qf[kc] = *(const bf16x8*)&Qp[(size_t)qabs * 128 + kc * 16 + hi * 8];

  // staging constants (K tile [32][128], V tile [128][32]); XOR swizzles
  const int kRow = tid >> 4;
  const int kCl = ((tid & 15) ^ (kRow & 7)) << 3;
  const int vRow = tid >> 2;
  const int vCl = ((tid & 3) ^ ((tid >> 3) & 3)) << 3;
  const int ldsoff = tid << 3;

  f32x16 ot[4] = {};
  float mrow = -1e30f, lsum = 0.f;
  const int nt = (qt << 2) + 4;
  const int nt_w = (qt << 2) + w + 1;
  const int swq = qi & 7, swv = (qi >> 1) & 3;

#pragma unroll
  for (int pt = 0; pt < 2; ++pt) {
    u16* bb = (u16*)lds[pt];
    gld_lds16(Kp + (size_t)((pt << 5) + kRow) * 128 + kCl, bb + ldsoff);
    gld_lds16(Kp + (size_t)((pt << 5) + kRow + 16) * 128 + kCl, bb + ldsoff + 2048);
    gld_lds16(Vp + (size_t)vRow * 2048 + (pt << 5) + vCl, bb + 4096 + ldsoff);
    gld_lds16(Vp + (size_t)(vRow + 64) * 2048 + (pt << 5) + vCl, bb + 4096 + ldsoff + 2048);
  }

  int bufc = 0;
  for (int t = 0; t < nt; ++t) {
    // drain stage(t) (oldest 4), keep stage(t+1) in flight
    asm volatile("s_waitcnt vmcnt(4)" ::: "memory");
    __builtin_amdgcn_sched_barrier(0);
    __builtin_amdgcn_s_barrier();
    {
      const int ts = (t + 2 < nt) ? t + 2 : nt - 1;  // clamped dummy keeps count
      const int bufn = bufc ? bufc - 1 : 2;          // (t+2)%3
      u16* bb = (u16*)lds[bufn];
      gld_lds16(Kp + (size_t)((ts << 5) + kRow) * 128 + kCl, bb + ldsoff);
      gld_lds16(Kp + (size_t)((ts << 5) + kRow + 16) * 128 + kCl, bb + ldsoff + 2048);
      gld_lds16(Vp + (size_t)vRow * 2048 + (ts << 5) + vCl, bb + 4096 + ldsoff);
      gld_lds16(Vp + (size_t)(vRow + 64) * 2048 + (ts << 5) + vCl, bb + 4096 + ldsoff + 2048);
    }
    if (t < nt_w) {
      const u16* kb_ = &lds[bufc][0];
      const u16* vb_ = &lds[bufc][4096];
      f32x16 st = {};
      __builtin_amdgcn_s_setprio(1);
#pragma unroll
      for (int kc = 0; kc < 8; ++kc) {
        bf16x8 kf = *(const bf16x8*)&kb_[(qi << 7) + ((((kc << 1) + hi) ^ swq) << 3)];
        st = mfma32(kf, qf[kc], st);
      }
      __builtin_amdgcn_s_setprio(0);

      if (t == nt_w - 1) {  // diagonal tile
        const int kb0 = t << 5;
#pragma unroll
        for (int reg = 0; reg < 16; ++reg) {
          int kk = kb0 + (reg & 3) + ((reg >> 2) << 3) + (hi << 2);
          if (kk > qabs) st[reg] = -1e30f;
        }
      }

      float tmax = st[0];
#pragma unroll
      for (int reg = 1; reg < 16; ++reg) tmax = fmaxf(tmax, st[reg]);
      tmax = fmaxf(tmax, __shfl_xor(tmax, 32));

      if (__any(tmax - mrow > 11.5f)) {  // defer-max, log2 units
        float nm = fmaxf(mrow, tmax);
        float al = __builtin_amdgcn_exp2f(mrow - nm);
        mrow = nm;
        lsum *= al;
#pragma unroll
        for (int db = 0; db < 4; ++db)
#pragma unroll
          for (int reg = 0; reg < 16; ++reg) ot[db][reg] *= al;
      }

      float psum = 0.f;
#pragma unroll
      for (int reg = 0; reg < 16; ++reg) {
        st[reg] = __builtin_amdgcn_exp2f(st[reg] - mrow);
        psum += st[reg];
      }
      psum += __shfl_xor(psum, 32);
      lsum += psum;

      bf16x8 pfrag[2];
#pragma unroll
      for (int bbp = 0; bbp < 2; ++bbp) {
        unsigned x0 = pk2(st[8 * bbp + 0], st[8 * bbp + 1]);
        unsigned x1 = pk2(st[8 * bbp + 2], st[8 * bbp + 3]);
        unsigned y0 = pk2(st[8 * bbp + 4], st[8 * bbp + 5]);
        unsigned y1 = pk2(st[8 * bbp + 6], st[8 * bbp + 7]);
        asm("v_permlane32_swap_b32 %0, %1" : "+v"(x0), "+v"(y0));
        asm("v_permlane32_swap_b32 %0, %1" : "+v"(x1), "+v"(y1));
        u32x4 uw = { x0, x1, y0, y1 };
        pfrag[bbp] = __builtin_bit_cast(bf16x8, uw);
      }

      __builtin_amdgcn_s_setprio(1);
#pragma unroll
      for (int db = 0; db < 4; ++db) {
        const u16* vr = &vb_[((db << 5) + qi) << 5];
#pragma unroll
        for (int ks = 0; ks < 2; ++ks) {
          bf16x8 vf = *(const bf16x8*)&vr[((((ks << 1) + hi)) ^ swv) << 3];
          ot[db] = mfma32(vf, pfrag[ks], ot[db]);
        }
      }
      __builtin_amdgcn_s_setprio(0);
    }
    bufc = (bufc == 2) ? 0 : bufc + 1;
  }

  float inv = 1.f / lsum;
  u16* rowp = attnO + (size_t)(b * 2048 + qabs) * 2048 + h * 128 + (hi << 2);
#pragma unroll
  for (int db = 0; db < 4; ++db)
#pragma unroll
    for (int mg = 0; mg < 4; ++mg) {
      u16x4 pkv = { f2b(ot[db][4 * mg + 0] * inv), f2b(ot[db][4 * mg + 1] * inv),
                    f2b(ot[db][4 * mg + 2] * inv), f2b(ot[db][4 * mg + 3] * inv) };
      *(u16x4*)&rowp[(db << 5) + (mg << 3)] = pkv;
    }
}

// ---------------------------------------------------------------------------
extern "C" void kernel_launch(void* const* d_in, const int* in_sizes, int n_in,
                              void* d_out, int out_size, void* d_ws, size_t ws_size,
                              hipStream_t stream) {
  const float* x  = (const float*)d_in[0];
  const float* Wq = (const float*)d_in[1];
  const float* Wk = (const float*)d_in[2];
  const float* Wv = (const float*)d_in[3];
  const float* Wo = (const float*)d_in[4];
  float* out = (float*)d_out;
  char* ws = (char*)d_ws;

  u16*   xb   = (u16*)(ws + 0);
  u16*   wqb  = (u16*)(ws + 16777216);
  u16*   wkb  = (u16*)(ws + 25165824);
  u16*   wvb  = (u16*)(ws + 27262976);
  u16*   wob  = (u16*)(ws + 29360128);
  float* cosT = (float*)(ws + 37748736);
  float* sinT = (float*)(ws + 46137344);
  float* Qtmp = (float*)(ws + 54525952);
  u16*   attnb= (u16*)(ws + 54525952);   // alias: Qtmp dead before attn
  float* Ktmp = (float*)(ws + 88080384);
  u16*   Qhp  = (u16*)(ws + 96468992);
  u16*   Khp  = (u16*)(ws + 113246208);
  u16*   Vtp  = (u16*)(ws + 130023424);

  cvt_all<<<18432, 256, 0, stream>>>((const float4*)x, (const float4*)Wq,
                                     (const float4*)Wk, (const float4*)Wv,
                                     (const float4*)Wo, (u16x4*)xb, (u16x4*)wqb,
                                     (u16x4*)wkb, (u16x4*)wvb, (u16x4*)wob);
  rope_table<<<8192, 256, 0, stream>>>(cosT, sinT);
  gemm_qkv<<<dim3(24, 32), 256, 0, stream>>>(xb, wqb, wkb, wvb, Qtmp, Ktmp, Vtp);
  rope_q<<<16384, 256, 0, stream>>>((const float2*)Qtmp, cosT, sinT, Qhp);
  rope_k<<<16384, 256, 0, stream>>>((const float2*)Ktmp, cosT, sinT, Khp);
  attn_kernel<<<512, 256, 0, stream>>>(Qhp, Khp, Vtp, attnb);
  gemm_bt<<<dim3(16, 32), 256, 0, stream>>>(attnb, wob, out, 4096, 2048, 2048);
}